// Round 2
// baseline (1244.848 us; speedup 1.0000x reference)
//
#include <hip/hip_runtime.h>

#define BB 64
#define TT 2048
#define II 64
#define HH 256
#define NTHR 512

typedef __fp16 h2_t __attribute__((ext_vector_type(2)));
typedef __fp16 h8_t __attribute__((ext_vector_type(8)));

#define H2(i) __builtin_bit_cast(h2_t, (i))
#define I32(h) __builtin_bit_cast(int, (h))

#if __has_builtin(__builtin_amdgcn_fdot2)
#define FDOT2(a, b, c) __builtin_amdgcn_fdot2((a), (b), (c), false)
#else
__device__ __forceinline__ float FDOT2(h2_t a, h2_t b, float c) {
    return fmaf((float)a[0], (float)b[0], fmaf((float)a[1], (float)b[1], c));
}
#endif

// tanh(x) = 1 - 2/(e^{2x}+1); v_exp + v_rcp, correct limits at +-inf.
__device__ __forceinline__ float ftanh(float x) {
    float e = __expf(2.0f * x);
    return 1.0f - 2.0f * __builtin_amdgcn_rcpf(e + 1.0f);
}

// DPP ctrl: 0xB1 quad_perm ^1, 0x4E quad_perm ^2, 0x140 ROW_MIRROR (^15),
// 0x141 ROW_HALF_MIRROR (^7), 0x142 ROW_BCAST15 (lane15->16..31, 47->48..63)
template <int CTRL>
__device__ __forceinline__ float dpp_add(float v) {
    int s = __builtin_amdgcn_update_dpp(0, __float_as_int(v), CTRL, 0xF, 0xF, true);
    return v + __int_as_float(s);
}
template <int CTRL>
__device__ __forceinline__ float dpp_get(float v) {
    int s = __builtin_amdgcn_update_dpp(0, __float_as_int(v), CTRL, 0xF, 0xF, true);
    return __int_as_float(s);
}
// true lane^4 exchange via ds_swizzle (arbitrary data, first merge level only)
template <int PAT>  // 0x101F = xor4
__device__ __forceinline__ float swz_get(float v) {
    return __int_as_float(__builtin_amdgcn_ds_swizzle(__float_as_int(v), PAT));
}

// merge-reduce: lo-lane keeps sum of a over the bit-pair, hi-lane keeps b.
__device__ __forceinline__ float mrg4(float a, float b, int lane) {
    float t = (lane & 4) ? b : a;
    float u = (lane & 4) ? a : b;
    return t + swz_get<0x101F>(u);
}
__device__ __forceinline__ float mrg2(float a, float b, int lane) {
    float t = (lane & 2) ? b : a;
    float u = (lane & 2) ? a : b;
    return t + dpp_get<0x4E>(u);
}

// R8: 512 threads = 8 waves = 2 waves/SIMD. The recurrence is latency-bound
// (R7: 1 wave/SIMD, per-SIMD VALU only ~66% busy, the rest is the bare serial
// tail reduce->tanh->write->barrier). Two co-resident waves fill each other's
// stalls; per-wave pinned weight tile halves to 80 VGPRs (4 rows x 32 cols),
// well under the 256-VGPR cap at 2 waves/SIMD.
// Each wave owns 32 rows; after mrg4+mrg2 the ^1 butterfly leaves each
// bit0-lane-pair duplicating one row: W_fc is pre-scaled by 0.5 and both
// lanes write the same h value to the same LDS address (2-way same-word,
// free per m136).
__launch_bounds__(NTHR, 2)
__global__ void rnn_fused(const float* __restrict__ x,
                          const float* __restrict__ W_ih,
                          const float* __restrict__ W_hh,
                          const float* __restrict__ b_ih,
                          const float* __restrict__ b_hh,
                          const float* __restrict__ W_fc,
                          const float* __restrict__ b_fc,
                          float* __restrict__ out) {
    // h fp16, double-buffered; 32-half chunks at 80 B stride: chunk q word jv
    // hits bank quad (20q+4jv)%32 -> disjoint -> conflict-free b128 reads.
    __shared__ __align__(16) __fp16 hbuf[2][320];
    // part[i+1] holds head partials of step i (deferred by one step); 16 = 8
    // waves x 2 half-sums. 2049*64B = 131 KB, fits the 160 KB LDS pool.
    __shared__ float part[TT + 1][16];

    const int tid  = threadIdx.x;
    const int b    = blockIdx.x;
    const int lane = tid & 63;
    const int wv   = tid >> 6;   // wave 0..7
    const int o    = lane >> 3;  // row sub-slot 0..7
    const int q    = lane & 7;   // k-slice 0..7

    // thread owns rows wv*32 + o*4 + r (r=0..3), cols [q*32, q*32+32)
    int whh_i[4][16];  // 64 VGPRs (fp16 pairs as int)
    int wih_i[4][4];   // 16 VGPRs
#pragma unroll
    for (int r = 0; r < 4; ++r) {
        const int t_r = wv * 32 + o * 4 + r;
        const float4* wr = (const float4*)(W_hh + t_r * HH + q * 32);
#pragma unroll
        for (int jv = 0; jv < 8; ++jv) {
            const float4 wv4 = wr[jv];
            whh_i[r][jv * 2 + 0] = I32(__builtin_amdgcn_cvt_pkrtz(wv4.x, wv4.y));
            whh_i[r][jv * 2 + 1] = I32(__builtin_amdgcn_cvt_pkrtz(wv4.z, wv4.w));
        }
        const float4* wi = (const float4*)(W_ih + t_r * II + q * 8);
        const float4 wa = wi[0], wb = wi[1];
        wih_i[r][0] = I32(__builtin_amdgcn_cvt_pkrtz(wa.x, wa.y));
        wih_i[r][1] = I32(__builtin_amdgcn_cvt_pkrtz(wa.z, wa.w));
        wih_i[r][2] = I32(__builtin_amdgcn_cvt_pkrtz(wb.x, wb.y));
        wih_i[r][3] = I32(__builtin_amdgcn_cvt_pkrtz(wb.z, wb.w));
    }
    // pin weights into VGPRs: asm def cannot be rematerialized from memory
#pragma unroll
    for (int j = 0; j < 64; ++j) asm volatile("" : "+v"(((int*)whh_i)[j]));
#pragma unroll
    for (int j = 0; j < 16; ++j) asm volatile("" : "+v"(((int*)wih_i)[j]));

    // final-row mapping after mrg4(bit2)+mrg2(bit1)+butterfly(bit0):
    // r_own = 2*bit2 + bit1; bit0-pairs duplicate the row.
    const int r_own = (lane >> 1) & 3;
    const int myrow = wv * 32 + o * 4 + r_own;
    const float bias = b_ih[myrow] + b_hh[myrow];
    const float wfc  = W_fc[myrow] * 0.5f;  // row appears in 2 lanes
    const float bfc  = b_fc[0];

    for (int idx = tid; idx < 2 * 320; idx += NTHR) ((__fp16*)hbuf)[idx] = (__fp16)0.0f;
    __syncthreads();

    const float* xbase = x + (size_t)b * TT * II + q * 8;
    float* outb = out + (size_t)b * TT;

    // h write address: row myrow lives at chunk wv (=myrow>>5), half myrow&31
    const int hoff = wv * 80 + (myrow & 31) * 2;  // bytes
    __fp16* hw0 = (__fp16*)((char*)&hbuf[0][0] + hoff);
    __fp16* hw1 = (__fp16*)((char*)&hbuf[1][0] + hoff);
    const h8_t* hp0 = (const h8_t*)((const char*)&hbuf[0][0] + q * 80);
    const h8_t* hp1 = (const h8_t*)((const char*)&hbuf[1][0] + q * 80);

    // x pipeline: xc = converted row i; slots A/B hold raw rows i+1, i+2
    h2_t xc[4];
    float4 sAa, sAc, sBa, sBc;
    {
        const float4* xp = (const float4*)(xbase);
        const float4 a = xp[0], c = xp[1];
        xc[0] = __builtin_amdgcn_cvt_pkrtz(a.x, a.y);
        xc[1] = __builtin_amdgcn_cvt_pkrtz(a.z, a.w);
        xc[2] = __builtin_amdgcn_cvt_pkrtz(c.x, c.y);
        xc[3] = __builtin_amdgcn_cvt_pkrtz(c.z, c.w);
        const float4* x1 = (const float4*)(xbase + II);
        sAa = x1[0]; sAc = x1[1];
        const float4* x2 = (const float4*)(xbase + 2 * II);
        sBa = x2[0]; sBc = x2[1];
    }

    float hn_prev = 0.0f;  // step-(-1) head -> part[0] (never read)

    // One step. HPIN: read buffer base (this step's h). HWOUT: write ptr for
    // h_{i+1}. SA/SC: raw x row IDX+1 (consumed; then refilled with IDX+3).
#define STEP(IDX, HPIN, HWOUT, SA, SC)                                         \
    {                                                                          \
        /* issue h reads first: latency overlaps deferred head + dot start */  \
        const h8_t hv0 = (HPIN)[0], hv1 = (HPIN)[1];                           \
        const h8_t hv2 = (HPIN)[2], hv3 = (HPIN)[3];                           \
        /* ---- deferred head of step IDX-1: pure-DPP 32-lane reduce ---- */   \
        {                                                                      \
            float c = hn_prev * wfc;                                           \
            c = dpp_add<0xB1>(c);   /* ^1 */                                   \
            c = dpp_add<0x4E>(c);   /* ^2 */                                   \
            c = dpp_add<0x141>(c);  /* ROW_HALF_MIRROR: eff ^4 */              \
            c = dpp_add<0x140>(c);  /* ROW_MIRROR: eff ^8 */                   \
            c = dpp_add<0x142>(c);  /* BCAST15: lanes 16/48 hold half-sums */  \
            if ((lane & 31) == 16) part[IDX][wv * 2 + (lane >> 5)] = c;        \
        }                                                                      \
        /* ---- dots: 4 rows x 32-col slice + 8-col input proj ---- */         \
        float a0 = 0, a1 = 0, a2 = 0, a3 = 0;                                  \
        _Pragma("unroll")                                                      \
        for (int jv = 0; jv < 4; ++jv) {                                       \
            const h8_t hv = (jv == 0) ? hv0 : (jv == 1) ? hv1                  \
                          : (jv == 2) ? hv2 : hv3;                             \
            _Pragma("unroll")                                                  \
            for (int e = 0; e < 4; ++e) {                                      \
                const h2_t he = (e == 0) ? __builtin_shufflevector(hv, hv, 0, 1) \
                              : (e == 1) ? __builtin_shufflevector(hv, hv, 2, 3) \
                              : (e == 2) ? __builtin_shufflevector(hv, hv, 4, 5) \
                                         : __builtin_shufflevector(hv, hv, 6, 7); \
                const int j = jv * 4 + e;                                      \
                a0 = FDOT2(H2(whh_i[0][j]), he, a0);                           \
                a1 = FDOT2(H2(whh_i[1][j]), he, a1);                           \
                a2 = FDOT2(H2(whh_i[2][j]), he, a2);                           \
                a3 = FDOT2(H2(whh_i[3][j]), he, a3);                           \
            }                                                                  \
        }                                                                      \
        _Pragma("unroll")                                                      \
        for (int e = 0; e < 4; ++e) {                                          \
            a0 = FDOT2(H2(wih_i[0][e]), xc[e], a0);                            \
            a1 = FDOT2(H2(wih_i[1][e]), xc[e], a1);                            \
            a2 = FDOT2(H2(wih_i[2][e]), xc[e], a2);                            \
            a3 = FDOT2(H2(wih_i[3][e]), xc[e], a3);                            \
        }                                                                      \
        /* consume slot (row IDX+1, landed >=2 steps ago), refill with IDX+3 */ \
        xc[0] = __builtin_amdgcn_cvt_pkrtz((SA).x, (SA).y);                    \
        xc[1] = __builtin_amdgcn_cvt_pkrtz((SA).z, (SA).w);                    \
        xc[2] = __builtin_amdgcn_cvt_pkrtz((SC).x, (SC).y);                    \
        xc[3] = __builtin_amdgcn_cvt_pkrtz((SC).z, (SC).w);                    \
        {                                                                      \
            const int rn = ((IDX) + 3 < TT) ? ((IDX) + 3) : (TT - 1);          \
            const float4* xp = (const float4*)(xbase + rn * II);               \
            (SA) = xp[0]; (SC) = xp[1];                                        \
        }                                                                      \
        /* ---- merge-reduce across the 8 k-slices ---- */                     \
        const float M0 = mrg4(a0, a2, lane);                                   \
        const float M1 = mrg4(a1, a3, lane);                                   \
        const float C0 = mrg2(M0, M1, lane);                                   \
        const float C  = C0 + dpp_get<0xB1>(C0);  /* bit0 butterfly: dup */    \
        const float hn = ftanh(C + bias);                                      \
        /* both bit0-lanes write same value to same address: free 2-way */     \
        (HWOUT)[0] = (__fp16)hn;                                               \
        hn_prev = hn;                                                          \
        /* LDS-only barrier: h_{IDX+1} visible; vmcnt NOT drained, so the */   \
        /* x prefetch loads stay in flight across steps */                     \
        asm volatile("s_waitcnt lgkmcnt(0)\n\ts_barrier" ::: "memory");        \
    }

    for (int ib = 0; ib < TT; ib += 2) {
        STEP(ib, hp0, hw1, sAa, sAc)
        STEP(ib + 1, hp1, hw0, sBa, sBc)
    }
#undef STEP

    // final head (step TT-1) -> part[TT]
    {
        float c = hn_prev * wfc;
        c = dpp_add<0xB1>(c);
        c = dpp_add<0x4E>(c);
        c = dpp_add<0x141>(c);
        c = dpp_add<0x140>(c);
        c = dpp_add<0x142>(c);
        if ((lane & 31) == 16) part[TT][wv * 2 + (lane >> 5)] = c;
    }
    __syncthreads();

    // ---- deferred output head: out[b][i] = sum(part[i+1][:]) + bfc ----
    for (int i = tid; i < TT; i += NTHR) {
        const float4* pp = (const float4*)&part[i + 1][0];
        const float4 s0 = pp[0], s1 = pp[1], s2 = pp[2], s3 = pp[3];
        outb[i] = s0.x + s0.y + s0.z + s0.w + s1.x + s1.y + s1.z + s1.w +
                  s2.x + s2.y + s2.z + s2.w + s3.x + s3.y + s3.z + s3.w + bfc;
    }
}

extern "C" void kernel_launch(void* const* d_in, const int* in_sizes, int n_in,
                              void* d_out, int out_size, void* d_ws, size_t ws_size,
                              hipStream_t stream) {
    const float* x    = (const float*)d_in[0];
    const float* W_ih = (const float*)d_in[1];
    const float* W_hh = (const float*)d_in[2];
    const float* b_ih = (const float*)d_in[3];
    const float* b_hh = (const float*)d_in[4];
    const float* W_fc = (const float*)d_in[5];
    const float* b_fc = (const float*)d_in[6];
    float* out = (float*)d_out;

    rnn_fused<<<BB, NTHR, 0, stream>>>(x, W_ih, W_hh, b_ih, b_hh, W_fc, b_fc, out);
}

// Round 4
// 1136.708 us; speedup vs baseline: 1.0951x; 1.0951x over previous
//
#include <hip/hip_runtime.h>

#define BB 64
#define TT 2048
#define II 64
#define HH 256
#define NTHR 256

typedef __fp16 h2_t __attribute__((ext_vector_type(2)));
typedef __fp16 h8_t __attribute__((ext_vector_type(8)));

#define H2(i) __builtin_bit_cast(h2_t, (i))
#define I32(h) __builtin_bit_cast(int, (h))

#if __has_builtin(__builtin_amdgcn_fdot2)
#define FDOT2(a, b, c) __builtin_amdgcn_fdot2((a), (b), (c), false)
#else
__device__ __forceinline__ float FDOT2(h2_t a, h2_t b, float c) {
    return fmaf((float)a[0], (float)b[0], fmaf((float)a[1], (float)b[1], c));
}
#endif

// tanh(x) = 1 - 2/(e^{2x}+1); v_exp + v_rcp, correct limits at +-inf.
__device__ __forceinline__ float ftanh(float x) {
    float e = __expf(2.0f * x);
    return 1.0f - 2.0f * __builtin_amdgcn_rcpf(e + 1.0f);
}

// DPP ctrl: 0xB1 quad_perm ^1, 0x4E quad_perm ^2, 0x124 row_ror:4,
// 0x12C row_ror:12, 0x140 ROW_MIRROR (^15 in row), 0x141 ROW_HALF_MIRROR
// (^7 in 8), 0x142 ROW_BCAST15 (lane15->16..31, 47->48..63)
// DIRECTION (derived from the canonical row_shr reduction idiom, R3 bug):
//   row_shr:N  = dst[i] <- src[i-N]   (data moves toward HIGHER lanes)
//   row_ror:N  = dst[i] <- src[(i-N) mod 16]
template <int CTRL>
__device__ __forceinline__ float dpp_add(float v) {
    int s = __builtin_amdgcn_update_dpp(0, __float_as_int(v), CTRL, 0xF, 0xF, true);
    return v + __int_as_float(s);
}
template <int CTRL>
__device__ __forceinline__ float dpp_get(float v) {
    int s = __builtin_amdgcn_update_dpp(0, __float_as_int(v), CTRL, 0xF, 0xF, true);
    return __int_as_float(s);
}

// merge-reduce, ALL-DPP. lane^4 exchange per 16-lane row:
//   bit2==0 lanes need src[i+4] = src[(i-12)%16] -> row_ror:12
//   bit2==1 lanes need src[i-4] = src[(i-4)%16]  -> row_ror:4
// (R3 had this selection inverted -> absmax 2.78; fixed here.)
__device__ __forceinline__ float mrg4(float a, float b, int lane) {
    float t = (lane & 4) ? b : a;
    float u = (lane & 4) ? a : b;
    float r4  = dpp_get<0x124>(u);
    float r12 = dpp_get<0x12C>(u);
    return t + ((lane & 4) ? r4 : r12);
}
__device__ __forceinline__ float mrg2(float a, float b, int lane) {
    float t = (lane & 2) ? b : a;
    float u = (lane & 2) ? a : b;
    return t + dpp_get<0x4E>(u);
}
__device__ __forceinline__ float mrg1(float a, float b, int lane) {
    float t = (lane & 1) ? b : a;
    float u = (lane & 1) ? a : b;
    return t + dpp_get<0xB1>(u);
}

// R4 (= R3 + mrg4 direction fix): 256 threads = 4 waves, 1 wave/SIMD.
//  - merge tree is pure DPP (4 ds_swizzles removed from the serial path)
//  - h stored as 4 chunks of 64 halves; each lane reads 8 cols from EACH
//    chunk (4x ds_read_b128 at bank 4q: zero conflicts, 8-lane broadcast).
//    Weight cols re-permuted to match.
//  - step order: barrier -> issue 4 h-reads -> head DPP reduce -> x-dots
//    (h-independent latency fill) -> h-dots chunk-wise (lgkm-pipelined) ->
//    merge -> tanh -> write own row -> lgkmcnt(0)+s_barrier (vmcnt NOT
//    drained: x prefetch stays in flight across steps).
__launch_bounds__(NTHR, 1)
__global__ void rnn_fused(const float* __restrict__ x,
                          const float* __restrict__ W_ih,
                          const float* __restrict__ W_hh,
                          const float* __restrict__ b_ih,
                          const float* __restrict__ b_hh,
                          const float* __restrict__ W_fc,
                          const float* __restrict__ b_fc,
                          float* __restrict__ out) {
    // hbuf[p][c][j] = h[c*64+j], fp16, double-buffered. Read addr = c*128 +
    // q*16 -> bank 4q, conflict-free; write addr = w*128 + lane*2 -> 2
    // lanes/word, free.
    __shared__ __align__(16) __fp16 hbuf[2][4][64];
    // part[i+1] holds head partials of step i (deferred by one step)
    __shared__ float part[TT + 1][8];

    const int tid  = threadIdx.x;
    const int b    = blockIdx.x;
    const int lane = tid & 63;
    const int w    = tid >> 6;   // wave 0..3
    const int o    = lane >> 3;  // row sub-slot 0..7
    const int q    = lane & 7;   // k-slice 0..7

    // thread owns rows w*64 + o*8 + r (r=0..7); cols: for chunk c in 0..3,
    // cols [c*64 + q*8, c*64 + q*8 + 8)  (32 cols total, chunk-interleaved)
    int whh_i[8][16];  // 128 VGPRs (fp16 pairs as int), j = c*4 + e
    int wih_i[8][4];   //  32 VGPRs
#pragma unroll
    for (int r = 0; r < 8; ++r) {
        const int t_r = w * 64 + o * 8 + r;
#pragma unroll
        for (int c = 0; c < 4; ++c) {
            const float4* wr = (const float4*)(W_hh + t_r * HH + c * 64 + q * 8);
            const float4 wa = wr[0], wb = wr[1];
            whh_i[r][c * 4 + 0] = I32(__builtin_amdgcn_cvt_pkrtz(wa.x, wa.y));
            whh_i[r][c * 4 + 1] = I32(__builtin_amdgcn_cvt_pkrtz(wa.z, wa.w));
            whh_i[r][c * 4 + 2] = I32(__builtin_amdgcn_cvt_pkrtz(wb.x, wb.y));
            whh_i[r][c * 4 + 3] = I32(__builtin_amdgcn_cvt_pkrtz(wb.z, wb.w));
        }
        const float4* wi = (const float4*)(W_ih + t_r * II + q * 8);
        const float4 wa = wi[0], wb = wi[1];
        wih_i[r][0] = I32(__builtin_amdgcn_cvt_pkrtz(wa.x, wa.y));
        wih_i[r][1] = I32(__builtin_amdgcn_cvt_pkrtz(wa.z, wa.w));
        wih_i[r][2] = I32(__builtin_amdgcn_cvt_pkrtz(wb.x, wb.y));
        wih_i[r][3] = I32(__builtin_amdgcn_cvt_pkrtz(wb.z, wb.w));
    }
    // pin weights into VGPRs: asm def cannot be rematerialized from memory
#pragma unroll
    for (int j = 0; j < 128; ++j) asm volatile("" : "+v"(((int*)whh_i)[j]));
#pragma unroll
    for (int j = 0; j < 32; ++j) asm volatile("" : "+v"(((int*)wih_i)[j]));

    // merge tree ends with lane owning row w*64+lane (harness-verified in R1;
    // tree unchanged, only column ORDER within each dot changed)
    const int myrow = w * 64 + lane;
    const float bias = b_ih[myrow] + b_hh[myrow];
    const float wfc  = W_fc[myrow];
    const float bfc  = b_fc[0];

    for (int idx = tid; idx < 2 * 256; idx += NTHR) ((__fp16*)hbuf)[idx] = (__fp16)0.0f;
    __syncthreads();

    const float* xbase = x + (size_t)b * TT * II + q * 8;
    float* outb = out + (size_t)b * TT;

    // write: own row -> chunk w, slot lane.  read: chunk c at q*16 bytes.
    char* hb0 = (char*)&hbuf[0][0][0];
    char* hb1 = (char*)&hbuf[1][0][0];
    __fp16* hw0 = (__fp16*)(hb0 + w * 128 + lane * 2);
    __fp16* hw1 = (__fp16*)(hb1 + w * 128 + lane * 2);
    const char* hq0 = hb0 + q * 16;
    const char* hq1 = hb1 + q * 16;

    // x pipeline: xc = converted row i; slots A/B hold raw rows i+1, i+2
    h2_t xc[4];
    float4 sAa, sAc, sBa, sBc;
    {
        const float4* xp = (const float4*)(xbase);
        const float4 a = xp[0], c = xp[1];
        xc[0] = __builtin_amdgcn_cvt_pkrtz(a.x, a.y);
        xc[1] = __builtin_amdgcn_cvt_pkrtz(a.z, a.w);
        xc[2] = __builtin_amdgcn_cvt_pkrtz(c.x, c.y);
        xc[3] = __builtin_amdgcn_cvt_pkrtz(c.z, c.w);
        const float4* x1 = (const float4*)(xbase + II);
        sAa = x1[0]; sAc = x1[1];
        const float4* x2 = (const float4*)(xbase + 2 * II);
        sBa = x2[0]; sBc = x2[1];
    }

    float hn_prev = 0.0f;  // step-(-1) head -> part[0] (never read)

    // One step. HRD: read base (this step's h buffer, at q*16). HWOUT: write
    // ptr for h_{i+1}. SA/SC: raw x row IDX+1 (consumed; refilled IDX+3).
#define STEP(IDX, HRD, HWOUT, SA, SC)                                          \
    {                                                                          \
        /* issue all 4 chunk reads first; latency hidden by head + x-dots */   \
        const h8_t hv0 = *(const h8_t*)((HRD) + 0 * 128);                      \
        const h8_t hv1 = *(const h8_t*)((HRD) + 1 * 128);                      \
        const h8_t hv2 = *(const h8_t*)((HRD) + 2 * 128);                      \
        const h8_t hv3 = *(const h8_t*)((HRD) + 3 * 128);                      \
        /* ---- deferred head of step IDX-1: pure-DPP 32-lane reduce ---- */   \
        {                                                                      \
            float hc = hn_prev * wfc;                                          \
            hc = dpp_add<0xB1>(hc);   /* ^1 */                                 \
            hc = dpp_add<0x4E>(hc);   /* ^2 */                                 \
            hc = dpp_add<0x141>(hc);  /* HALF_MIRROR: eff ^4 */                \
            hc = dpp_add<0x140>(hc);  /* ROW_MIRROR: eff ^8 */                 \
            hc = dpp_add<0x142>(hc);  /* BCAST15: lanes 16/48 hold sums */     \
            if ((lane & 31) == 16) part[IDX][w * 2 + (lane >> 5)] = hc;        \
        }                                                                      \
        /* ---- x-dots first: h-independent, fills h-read latency ---- */      \
        float a0, a1, a2, a3, a4, a5, a6, a7;                                  \
        a0 = FDOT2(H2(wih_i[0][0]), xc[0], 0.0f);                              \
        a1 = FDOT2(H2(wih_i[1][0]), xc[0], 0.0f);                              \
        a2 = FDOT2(H2(wih_i[2][0]), xc[0], 0.0f);                              \
        a3 = FDOT2(H2(wih_i[3][0]), xc[0], 0.0f);                              \
        a4 = FDOT2(H2(wih_i[4][0]), xc[0], 0.0f);                              \
        a5 = FDOT2(H2(wih_i[5][0]), xc[0], 0.0f);                              \
        a6 = FDOT2(H2(wih_i[6][0]), xc[0], 0.0f);                              \
        a7 = FDOT2(H2(wih_i[7][0]), xc[0], 0.0f);                              \
        _Pragma("unroll")                                                      \
        for (int e = 1; e < 4; ++e) {                                          \
            a0 = FDOT2(H2(wih_i[0][e]), xc[e], a0);                            \
            a1 = FDOT2(H2(wih_i[1][e]), xc[e], a1);                            \
            a2 = FDOT2(H2(wih_i[2][e]), xc[e], a2);                            \
            a3 = FDOT2(H2(wih_i[3][e]), xc[e], a3);                            \
            a4 = FDOT2(H2(wih_i[4][e]), xc[e], a4);                            \
            a5 = FDOT2(H2(wih_i[5][e]), xc[e], a5);                            \
            a6 = FDOT2(H2(wih_i[6][e]), xc[e], a6);                            \
            a7 = FDOT2(H2(wih_i[7][e]), xc[e], a7);                            \
        }                                                                      \
        /* consume x slot (row IDX+1), refill with row IDX+3 */                \
        xc[0] = __builtin_amdgcn_cvt_pkrtz((SA).x, (SA).y);                    \
        xc[1] = __builtin_amdgcn_cvt_pkrtz((SA).z, (SA).w);                    \
        xc[2] = __builtin_amdgcn_cvt_pkrtz((SC).x, (SC).y);                    \
        xc[3] = __builtin_amdgcn_cvt_pkrtz((SC).z, (SC).w);                    \
        {                                                                      \
            const int rn = ((IDX) + 3 < TT) ? ((IDX) + 3) : (TT - 1);          \
            const float4* xp = (const float4*)(xbase + rn * II);               \
            (SA) = xp[0]; (SC) = xp[1];                                        \
        }                                                                      \
        /* ---- h-dots: chunk-wise, lgkm-pipelined by the compiler ---- */     \
        _Pragma("unroll")                                                      \
        for (int c = 0; c < 4; ++c) {                                          \
            const h8_t hv = (c == 0) ? hv0 : (c == 1) ? hv1                    \
                          : (c == 2) ? hv2 : hv3;                              \
            _Pragma("unroll")                                                  \
            for (int e = 0; e < 4; ++e) {                                      \
                const h2_t he = (e == 0) ? __builtin_shufflevector(hv, hv, 0, 1) \
                              : (e == 1) ? __builtin_shufflevector(hv, hv, 2, 3) \
                              : (e == 2) ? __builtin_shufflevector(hv, hv, 4, 5) \
                                         : __builtin_shufflevector(hv, hv, 6, 7); \
                const int j = c * 4 + e;                                       \
                a0 = FDOT2(H2(whh_i[0][j]), he, a0);                           \
                a1 = FDOT2(H2(whh_i[1][j]), he, a1);                           \
                a2 = FDOT2(H2(whh_i[2][j]), he, a2);                           \
                a3 = FDOT2(H2(whh_i[3][j]), he, a3);                           \
                a4 = FDOT2(H2(whh_i[4][j]), he, a4);                           \
                a5 = FDOT2(H2(whh_i[5][j]), he, a5);                           \
                a6 = FDOT2(H2(whh_i[6][j]), he, a6);                           \
                a7 = FDOT2(H2(whh_i[7][j]), he, a7);                           \
            }                                                                  \
        }                                                                      \
        /* ---- merge-reduce (pure DPP, no LDS ops) ---- */                    \
        const float A0 = mrg4(a0, a4, lane);                                   \
        const float A1 = mrg4(a1, a5, lane);                                   \
        const float A2 = mrg4(a2, a6, lane);                                   \
        const float A3 = mrg4(a3, a7, lane);                                   \
        const float B0 = mrg2(A0, A2, lane);                                   \
        const float B1 = mrg2(A1, A3, lane);                                   \
        const float C0 = mrg1(B0, B1, lane);                                   \
        const float hn = ftanh(C0 + bias);                                     \
        (HWOUT)[0] = (__fp16)hn;                                               \
        hn_prev = hn;                                                          \
        /* LDS-only barrier: h_{IDX+1} visible; vmcnt NOT drained */           \
        asm volatile("s_waitcnt lgkmcnt(0)\n\ts_barrier" ::: "memory");        \
    }

    for (int ib = 0; ib < TT; ib += 2) {
        STEP(ib, hq0, hw1, sAa, sAc)
        STEP(ib + 1, hq1, hw0, sBa, sBc)
    }
#undef STEP

    // final head (step TT-1) -> part[TT]
    {
        float hc = hn_prev * wfc;
        hc = dpp_add<0xB1>(hc);
        hc = dpp_add<0x4E>(hc);
        hc = dpp_add<0x141>(hc);
        hc = dpp_add<0x140>(hc);
        hc = dpp_add<0x142>(hc);
        if ((lane & 31) == 16) part[TT][w * 2 + (lane >> 5)] = hc;
    }
    __syncthreads();

    // ---- deferred output head: out[b][i] = sum(part[i+1][:]) + bfc ----
    for (int i = tid; i < TT; i += NTHR) {
        const float4* pp = (const float4*)&part[i + 1][0];
        const float4 s0 = pp[0], s1 = pp[1];
        outb[i] = s0.x + s0.y + s0.z + s0.w + s1.x + s1.y + s1.z + s1.w + bfc;
    }
}

extern "C" void kernel_launch(void* const* d_in, const int* in_sizes, int n_in,
                              void* d_out, int out_size, void* d_ws, size_t ws_size,
                              hipStream_t stream) {
    const float* x    = (const float*)d_in[0];
    const float* W_ih = (const float*)d_in[1];
    const float* W_hh = (const float*)d_in[2];
    const float* b_ih = (const float*)d_in[3];
    const float* b_hh = (const float*)d_in[4];
    const float* W_fc = (const float*)d_in[5];
    const float* b_fc = (const float*)d_in[6];
    float* out = (float*)d_out;

    rnn_fused<<<BB, NTHR, 0, stream>>>(x, W_ih, W_hh, b_ih, b_hh, W_fc, b_fc, out);
}